// Round 4
// baseline (608.219 us; speedup 1.0000x reference)
//
#include <hip/hip_runtime.h>
#include <hip/hip_bf16.h>

typedef _Float16 half8 __attribute__((ext_vector_type(8)));
typedef float float4v __attribute__((ext_vector_type(4)));

#define D_IN 1024
#define D_PROJ 128
#define KSTEPS 32   // D_IN / 32
#define CTILES 8    // D_PROJ / 16

// Pre-pass: convert W [128][1024] f32 -> f16 in MFMA B-fragment order.
// Fragment f = ks*8 + ct; lane l holds B[k=(l>>4)*8+j][col=l&15]
//   = W[ct*16 + (l&15)][ks*32 + (l>>4)*8 + j],  j=0..7 contiguous.
__global__ __launch_bounds__(256) void wconv_kernel(const float* __restrict__ W,
                                                    _Float16* __restrict__ wf) {
    int t = blockIdx.x * 256 + threadIdx.x;   // 32*8*64 = 16384 threads
    int l  = t & 63;
    int ct = (t >> 6) & 7;
    int ks = t >> 9;
    const float* src = W + (size_t)(ct * 16 + (l & 15)) * D_IN + ks * 32 + ((l >> 4) * 8);
    float4v lo = *reinterpret_cast<const float4v*>(src);
    float4v hi = *reinterpret_cast<const float4v*>(src + 4);
    half8 h;
#pragma unroll
    for (int j = 0; j < 4; ++j) {
        h[j]     = (_Float16)lo[j];
        h[j + 4] = (_Float16)hi[j];
    }
    *reinterpret_cast<half8*>(wf + (size_t)t * 8) = h;
}

__device__ __forceinline__ float fast_tanh(float x) {
    // tanh(x) = 1 - 2/(exp2(2*log2e*x)+1); v_exp_f32-based; |z| ≲ 4 here so no overflow
    float e = __builtin_amdgcn_exp2f(x * 2.885390081777927f);
    return 1.0f - 2.0f / (e + 1.0f);
}

__global__ __launch_bounds__(256) void fused_kernel(const float* __restrict__ x1,
                                                    const float* __restrict__ x2,
                                                    const _Float16* __restrict__ wf,
                                                    const float* __restrict__ b,
                                                    float* __restrict__ out) {
    const int l    = threadIdx.x & 63;
    const int wave = threadIdx.x >> 6;
    const int rowBase = blockIdx.x * 64 + wave * 16;
    const int lr = l & 15;   // A-row / B-col within 16-tile
    const int lg = l >> 4;   // k-group (covers 8 consecutive k)

    const float4v* p1 = reinterpret_cast<const float4v*>(
        x1 + (size_t)(rowBase + lr) * D_IN + lg * 8);
    const float4v* p2 = reinterpret_cast<const float4v*>(
        x2 + (size_t)(rowBase + lr) * D_IN + lg * 8);
    const half8* wfrag = reinterpret_cast<const half8*>(wf) + l;  // + (ks*8+ct)*64

    float4v acc1[CTILES], acc2[CTILES];
#pragma unroll
    for (int ct = 0; ct < CTILES; ++ct) {
        acc1[ct] = (float4v){0.f, 0.f, 0.f, 0.f};
        acc2[ct] = (float4v){0.f, 0.f, 0.f, 0.f};
    }

#pragma unroll 2
    for (int ks = 0; ks < KSTEPS; ++ks) {
        // +ks*32 floats = +8 float4v; x1/x2 are streamed once -> non-temporal
        float4v a1lo = __builtin_nontemporal_load(p1 + ks * 8);
        float4v a1hi = __builtin_nontemporal_load(p1 + ks * 8 + 1);
        float4v a2lo = __builtin_nontemporal_load(p2 + ks * 8);
        float4v a2hi = __builtin_nontemporal_load(p2 + ks * 8 + 1);
        half8 a1, a2;
#pragma unroll
        for (int j = 0; j < 4; ++j) {
            a1[j]     = (_Float16)a1lo[j];
            a1[j + 4] = (_Float16)a1hi[j];
            a2[j]     = (_Float16)a2lo[j];
            a2[j + 4] = (_Float16)a2hi[j];
        }
        const half8* wp = wfrag + (size_t)ks * 8 * 64;
#pragma unroll
        for (int ct = 0; ct < CTILES; ++ct) {
            half8 bw = wp[ct * 64];
            acc1[ct] = __builtin_amdgcn_mfma_f32_16x16x32_f16(a1, bw, acc1[ct], 0, 0, 0);
            acc2[ct] = __builtin_amdgcn_mfma_f32_16x16x32_f16(a2, bw, acc2[ct], 0, 0, 0);
        }
    }

    // Epilogue: bias + tanh + row-dot + sigmoid.
    // C layout: col = l&15, row = (l>>4)*4 + reg  [m89-verified, dtype-independent]
    float bias[CTILES];
#pragma unroll
    for (int ct = 0; ct < CTILES; ++ct) bias[ct] = b[ct * 16 + lr];

    float s[4] = {0.f, 0.f, 0.f, 0.f};
#pragma unroll
    for (int ct = 0; ct < CTILES; ++ct) {
#pragma unroll
        for (int r = 0; r < 4; ++r) {
            float t1 = fast_tanh(acc1[ct][r] + bias[ct]);
            float t2 = fast_tanh(acc2[ct][r] + bias[ct]);
            s[r] += t1 * t2;
        }
    }
#pragma unroll
    for (int r = 0; r < 4; ++r) {
        float v = s[r];
        v += __shfl_xor(v, 1);
        v += __shfl_xor(v, 2);
        v += __shfl_xor(v, 4);
        v += __shfl_xor(v, 8);
        if (lr == 0) {
            int row = rowBase + lg * 4 + r;
            float e = __builtin_amdgcn_exp2f(-v * 1.4426950408889634f);
            out[row] = 1.0f / (1.0f + e);
        }
    }
}

extern "C" void kernel_launch(void* const* d_in, const int* in_sizes, int n_in,
                              void* d_out, int out_size, void* d_ws, size_t ws_size,
                              hipStream_t stream) {
    const float* x1 = (const float*)d_in[0];
    const float* x2 = (const float*)d_in[1];
    const float* W  = (const float*)d_in[2];
    const float* b  = (const float*)d_in[3];
    float* out = (float*)d_out;
    _Float16* wf = (_Float16*)d_ws;   // 128*1024*2 = 256 KiB fragment-ordered W

    // 16384 threads = 64 blocks
    hipLaunchKernelGGL(wconv_kernel, dim3(64), dim3(256), 0, stream, W, wf);
    // 65536 rows / 64 rows-per-block = 1024 blocks
    hipLaunchKernelGGL(fused_kernel, dim3(1024), dim3(256), 0, stream,
                       x1, x2, wf, b, out);
}

// Round 5
// 567.334 us; speedup vs baseline: 1.0721x; 1.0721x over previous
//
#include <hip/hip_runtime.h>
#include <hip/hip_bf16.h>

typedef _Float16 half8 __attribute__((ext_vector_type(8)));
typedef _Float16 half4 __attribute__((ext_vector_type(4)));
typedef float float4v __attribute__((ext_vector_type(4)));

#define D_IN 1024
#define D_PROJ 128
#define CTILES 8        // 128 cols / 16
#define NPH 8           // phases of 128 k each
#define SLOTS 8         // global-load instrs per input per phase (2 rows x 512B each)
#define ROWSTRIDE 272   // 128 f16 = 256B + 16B pad (16B-aligned, breaks bank stride)
#define WAVE_LDS (2 * 16 * ROWSTRIDE)   // 8704 B per wave (2 inputs x 16 rows)

// Pre-pass: convert W [128][1024] f32 -> f16 in MFMA B-fragment order.
// Fragment f = ks*8 + ct; lane l holds B[k=(l>>4)*8+j][col=l&15]
//   = W[ct*16 + (l&15)][ks*32 + (l>>4)*8 + j],  j=0..7 contiguous.
__global__ __launch_bounds__(256) void wconv_kernel(const float* __restrict__ W,
                                                    _Float16* __restrict__ wf) {
    int t = blockIdx.x * 256 + threadIdx.x;   // 32*8*64 = 16384 threads
    int l  = t & 63;
    int ct = (t >> 6) & 7;
    int ks = t >> 9;
    const float* src = W + (size_t)(ct * 16 + (l & 15)) * D_IN + ks * 32 + ((l >> 4) * 8);
    float4v lo = *reinterpret_cast<const float4v*>(src);
    float4v hi = *reinterpret_cast<const float4v*>(src + 4);
    half8 h;
#pragma unroll
    for (int j = 0; j < 4; ++j) {
        h[j]     = (_Float16)lo[j];
        h[j + 4] = (_Float16)hi[j];
    }
    *reinterpret_cast<half8*>(wf + (size_t)t * 8) = h;
}

__device__ __forceinline__ float fast_tanh(float x) {
    // tanh(x) = 1 - 2/(exp2(2*log2e*x)+1); |z| <~ 4 here so no overflow
    float e = __builtin_amdgcn_exp2f(x * 2.885390081777927f);
    return 1.0f - 2.0f / (e + 1.0f);
}

__global__ __launch_bounds__(256, 2) void fused_kernel(const float* __restrict__ x1,
                                                       const float* __restrict__ x2,
                                                       const _Float16* __restrict__ wf,
                                                       const float* __restrict__ b,
                                                       float* __restrict__ out) {
    // Per-wave-private LDS staging: no cross-wave barriers anywhere.
    __shared__ __align__(16) char smem[4 * WAVE_LDS];

    const int l    = threadIdx.x & 63;
    const int wave = threadIdx.x >> 6;
    const int rowBase = blockIdx.x * 64 + wave * 16;
    const int lr = l & 15;   // fragment A-row / B-col
    const int lg = l >> 4;   // fragment k-group

    char* ldsA = smem + wave * WAVE_LDS;           // x1 tile [16][128] f16, padded rows
    char* ldsB = ldsA + 16 * ROWSTRIDE;            // x2 tile

    // Coalesced load base: lanes 0-31 -> row (2i), lanes 32-63 -> row (2i+1),
    // each half-wave reads a 512B contiguous run of its row.
    const char* g1 = (const char*)x1 + (((size_t)(rowBase + (l >> 5))) << 12) + ((l & 31) << 4);
    const char* g2 = (const char*)x2 + (((size_t)(rowBase + (l >> 5))) << 12) + ((l & 31) << 4);

    const half8* wfrag = reinterpret_cast<const half8*>(wf) + l;  // + (ks_g*8+ct)*64

    float4v acc1[CTILES], acc2[CTILES];
#pragma unroll
    for (int ct = 0; ct < CTILES; ++ct) {
        acc1[ct] = (float4v){0.f, 0.f, 0.f, 0.f};
        acc2[ct] = (float4v){0.f, 0.f, 0.f, 0.f};
    }

    // Single prefetch buffer: loads for phase ph+1 are issued after cvt(ph)
    // consumed the registers (pure program-order WAR, no hazard).
    float4v P1[SLOTS], P2[SLOTS];
#pragma unroll
    for (int i = 0; i < SLOTS; ++i) {
        P1[i] = *reinterpret_cast<const float4v*>(g1 + i * 8192);
        P2[i] = *reinterpret_cast<const float4v*>(g2 + i * 8192);
    }

    const int woff = (l >> 5) * ROWSTRIDE + (l & 31) * 8;  // within-tile write offset

#pragma unroll
    for (int ph = 0; ph < NPH; ++ph) {
        // 1) convert current phase to f16 (frees P for the next-phase loads)
        half4 h1[SLOTS], h2[SLOTS];
#pragma unroll
        for (int i = 0; i < SLOTS; ++i) {
#pragma unroll
            for (int j = 0; j < 4; ++j) {
                h1[i][j] = (_Float16)P1[i][j];
                h2[i][j] = (_Float16)P2[i][j];
            }
        }
        // 2) issue next-phase global loads (overlap HBM latency with MFMA below)
        if (ph + 1 < NPH) {
#pragma unroll
            for (int i = 0; i < SLOTS; ++i) {
                P1[i] = *reinterpret_cast<const float4v*>(g1 + (ph + 1) * 512 + i * 8192);
                P2[i] = *reinterpret_cast<const float4v*>(g2 + (ph + 1) * 512 + i * 8192);
            }
        }
        // 3) stage f16 tile into this wave's private LDS region
#pragma unroll
        for (int i = 0; i < SLOTS; ++i) {
            *reinterpret_cast<half4*>(ldsA + 2 * i * ROWSTRIDE + woff) = h1[i];
            *reinterpret_cast<half4*>(ldsB + 2 * i * ROWSTRIDE + woff) = h2[i];
        }
        // Same-wave DS pipe is in-order; fence compiler + HW before fragment reads.
        asm volatile("s_waitcnt lgkmcnt(0)" ::: "memory");
        __builtin_amdgcn_sched_barrier(0);

        // 4) fragment reads + MFMA (identical fragment layout to verified kernel)
#pragma unroll
        for (int ks = 0; ks < 4; ++ks) {
            half8 a1 = *reinterpret_cast<const half8*>(ldsA + lr * ROWSTRIDE + ks * 64 + lg * 16);
            half8 a2 = *reinterpret_cast<const half8*>(ldsB + lr * ROWSTRIDE + ks * 64 + lg * 16);
            const half8* wp = wfrag + (size_t)(ph * 4 + ks) * 8 * 64;
#pragma unroll
            for (int ct = 0; ct < CTILES; ++ct) {
                half8 bw = wp[ct * 64];
                acc1[ct] = __builtin_amdgcn_mfma_f32_16x16x32_f16(a1, bw, acc1[ct], 0, 0, 0);
                acc2[ct] = __builtin_amdgcn_mfma_f32_16x16x32_f16(a2, bw, acc2[ct], 0, 0, 0);
            }
        }
    }

    // Epilogue: bias + tanh + row-dot + sigmoid.
    // C layout: col = l&15, row = (l>>4)*4 + reg  [m89-verified, dtype-independent]
    float bias[CTILES];
#pragma unroll
    for (int ct = 0; ct < CTILES; ++ct) bias[ct] = b[ct * 16 + lr];

    float s[4] = {0.f, 0.f, 0.f, 0.f};
#pragma unroll
    for (int ct = 0; ct < CTILES; ++ct) {
#pragma unroll
        for (int r = 0; r < 4; ++r) {
            float t1 = fast_tanh(acc1[ct][r] + bias[ct]);
            float t2 = fast_tanh(acc2[ct][r] + bias[ct]);
            s[r] += t1 * t2;
        }
    }
#pragma unroll
    for (int r = 0; r < 4; ++r) {
        float v = s[r];
        v += __shfl_xor(v, 1);
        v += __shfl_xor(v, 2);
        v += __shfl_xor(v, 4);
        v += __shfl_xor(v, 8);
        if (lr == 0) {
            int row = rowBase + lg * 4 + r;
            float e = __builtin_amdgcn_exp2f(-v * 1.4426950408889634f);
            out[row] = 1.0f / (1.0f + e);
        }
    }
}

extern "C" void kernel_launch(void* const* d_in, const int* in_sizes, int n_in,
                              void* d_out, int out_size, void* d_ws, size_t ws_size,
                              hipStream_t stream) {
    const float* x1 = (const float*)d_in[0];
    const float* x2 = (const float*)d_in[1];
    const float* W  = (const float*)d_in[2];
    const float* b  = (const float*)d_in[3];
    float* out = (float*)d_out;
    _Float16* wf = (_Float16*)d_ws;   // 128*1024*2 = 256 KiB fragment-ordered W

    hipLaunchKernelGGL(wconv_kernel, dim3(64), dim3(256), 0, stream, W, wf);
    hipLaunchKernelGGL(fused_kernel, dim3(1024), dim3(256), 0, stream,
                       x1, x2, wf, b, out);
}